// Round 2
// baseline (577.710 us; speedup 1.0000x reference)
//
#include <hip/hip_runtime.h>

// Round 1: fix patchify OOB (grid 16384 -> 4096: x has 1,048,576 float4s),
// alias y_att onto tok (ws 176.5 -> 144.5 MB). Pipeline unchanged:
// patchify -> conv GEMM -> fused QKV GEMM (writes present to d_out) ->
// flash attention (online softmax) -> proj GEMM.
// GEMMs: m97-style 128x128 tile, BK=32, global_load_lds width=16,
// mfma_f32_16x16x32_bf16; A/B frag: idx=lane&15, k=(lane>>4)*8+j;
// C/D: col=lane&15, row=(lane>>4)*4+reg.

typedef unsigned short u16;
typedef unsigned int u32;
typedef __attribute__((ext_vector_type(8))) short bf16x8;
typedef __attribute__((ext_vector_type(4))) float f32x4;
typedef __attribute__((ext_vector_type(4))) u16 u16x4;

#define Y_ELEMS  16777216   // B*T*C = 64*256*1024
#define KV_ELEMS 16777216   // B*H*T*D

__device__ __forceinline__ u16 f2b(float f) {
  u32 u = __float_as_uint(f);
  u32 r = u + 0x7fffu + ((u >> 16) & 1u);
  return (u16)(r >> 16);
}

__device__ __forceinline__ void gl_lds16(const u16* g, u16* l) {
  __builtin_amdgcn_global_load_lds(
      (__attribute__((address_space(1))) void*)g,
      (__attribute__((address_space(3))) void*)l, 16, 0, 0);
}

// ---------------- patchify: x[64,1,256,256] -> A_patch bf16 [16384,256] ----
// one float4 of x per thread; 1,048,576 float4s total -> 4096 blocks.
__global__ __launch_bounds__(256) void patchify_kernel(
    const float* __restrict__ x, u16* __restrict__ ap) {
  int tid = blockIdx.x * 256 + threadIdx.x;
  float4 v = ((const float4*)x)[tid];
  int col4 = tid & 63;           // float4 index within image row (64 per row)
  int row  = (tid >> 6) & 255;   // image row within image
  int b    = tid >> 14;          // 16384 float4 per image
  int py = row >> 4, ky = row & 15;
  int col = col4 << 2;
  int px = col >> 4, kx = col & 15;   // kx in {0,4,8,12}: 4 pixels stay in patch row
  size_t dst = ((size_t)(b * 256 + py * 16 + px)) * 256 + ky * 16 + kx;
  u16x4 o = { f2b(v.x), f2b(v.y), f2b(v.z), f2b(v.w) };
  *(u16x4*)(ap + dst) = o;
}

// ---------------- conv_w [1024,256] fp32 -> bf16 (already N x K) -----------
__global__ __launch_bounds__(256) void castw_kernel(
    const float* __restrict__ w, u16* __restrict__ o) {
  int tid = blockIdx.x * 256 + threadIdx.x;
  float4 v = ((const float4*)w)[tid];
  u16x4 q = { f2b(v.x), f2b(v.y), f2b(v.z), f2b(v.w) };
  *(u16x4*)(o + (size_t)tid * 4) = q;
}

// ---------------- transpose Wq/Wk/Wv -> Wqkv_t [3072,1024] bf16, Wp -> Wp_t -
__global__ __launch_bounds__(256) void transpose_w_kernel(
    const float* __restrict__ Wq, const float* __restrict__ Wk,
    const float* __restrict__ Wv, const float* __restrict__ Wp,
    u16* __restrict__ Wqkv_t, u16* __restrict__ Wp_t) {
  __shared__ float tile[32][33];
  int z = blockIdx.z;
  const float* W = (z == 0) ? Wq : (z == 1) ? Wk : (z == 2) ? Wv : Wp;
  u16* dst = (z < 3) ? (Wqkv_t + (size_t)z * 1024 * 1024) : Wp_t;
  int x0 = blockIdx.x * 32, y0 = blockIdx.y * 32;
  int tx = threadIdx.x, ty = threadIdx.y;
#pragma unroll
  for (int i = ty; i < 32; i += 8)
    tile[i][tx] = W[(size_t)(y0 + i) * 1024 + x0 + tx];
  __syncthreads();
#pragma unroll
  for (int i = ty; i < 32; i += 8)
    dst[(size_t)(x0 + i) * 1024 + y0 + tx] = f2b(tile[tx][i]);
}

// ---------------- NT GEMM: A[M,K] bf16 row-major, Bt[N,K] bf16 row-major ---
// mode 0: tok = A*B + bias0 -> ob0 bf16 [M,N]
// mode 1: fused qkv (N=3072): seg0->q_ws bf16 [bh,t,d]; seg1->k fp32 d_out + k_ws bf16;
//         seg2->v fp32 d_out + v_t bf16 [bh,d,t]
// mode 2: y = A*B + bias0 -> of0 fp32 [M,N]
__global__ __launch_bounds__(256) void gemm_kernel(
    const u16* __restrict__ A, const u16* __restrict__ Bt,
    int K, int N, int mode,
    const float* __restrict__ bias0, const float* __restrict__ bias1,
    const float* __restrict__ bias2,
    u16* __restrict__ ob0, u16* __restrict__ ob1, u16* __restrict__ ob2,
    float* __restrict__ of0) {
  __shared__ __attribute__((aligned(16))) u16 As[128 * 32];
  __shared__ __attribute__((aligned(16))) u16 Bs[128 * 32];
  const int t = threadIdx.x;
  const int rr = t >> 2;
  const int c8 = (t & 3) << 3;
  const int lane = t & 63;
  const int w = t >> 6;
  const int wm = (w & 1) << 6, wn = (w >> 1) << 6;
  const int l15 = lane & 15, quad = lane >> 4;
  const int tile_m = blockIdx.x * 128, tile_n = blockIdx.y * 128;

  f32x4 acc[4][4];
  f32x4 zero = {0.f, 0.f, 0.f, 0.f};
#pragma unroll
  for (int i = 0; i < 4; ++i)
#pragma unroll
    for (int j = 0; j < 4; ++j) acc[i][j] = zero;

  const u16* gA0 = A + (size_t)(tile_m + rr) * K + c8;
  const u16* gA1 = A + (size_t)(tile_m + 64 + rr) * K + c8;
  const u16* gB0 = Bt + (size_t)(tile_n + rr) * K + c8;
  const u16* gB1 = Bt + (size_t)(tile_n + 64 + rr) * K + c8;
  u16* lA0 = As + rr * 32 + c8;
  u16* lA1 = As + (64 + rr) * 32 + c8;
  u16* lB0 = Bs + rr * 32 + c8;
  u16* lB1 = Bs + (64 + rr) * 32 + c8;

  for (int k0 = 0; k0 < K; k0 += 32) {
    __syncthreads();
    gl_lds16(gA0 + k0, lA0);
    gl_lds16(gA1 + k0, lA1);
    gl_lds16(gB0 + k0, lB0);
    gl_lds16(gB1 + k0, lB1);
    __syncthreads();
    bf16x8 af[4], bfr[4];
#pragma unroll
    for (int i = 0; i < 4; ++i)
      af[i] = *(const bf16x8*)(As + (wm + 16 * i + l15) * 32 + quad * 8);
#pragma unroll
    for (int j = 0; j < 4; ++j)
      bfr[j] = *(const bf16x8*)(Bs + (wn + 16 * j + l15) * 32 + quad * 8);
#pragma unroll
    for (int i = 0; i < 4; ++i)
#pragma unroll
      for (int j = 0; j < 4; ++j)
        acc[i][j] = __builtin_amdgcn_mfma_f32_16x16x32_bf16(af[i], bfr[j], acc[i][j], 0, 0, 0);
  }

#pragma unroll
  for (int i = 0; i < 4; ++i) {
#pragma unroll
    for (int j = 0; j < 4; ++j) {
      int n = tile_n + wn + 16 * j + l15;
      if (mode == 1) {
        int seg = n >> 10, nn = n & 1023;
        const float* bptr = (seg == 0) ? bias0 : (seg == 1) ? bias1 : bias2;
        float bias = bptr[nn];
        int h = nn >> 7, d = nn & 127;
#pragma unroll
        for (int r = 0; r < 4; ++r) {
          int m = tile_m + wm + 16 * i + quad * 4 + r;
          int bb = m >> 8, tt = m & 255;
          int bh = bb * 8 + h;
          float v = acc[i][j][r] + bias;
          size_t idx = ((size_t)bh * 256 + tt) * 128 + d;
          if (seg == 0) {
            ob0[idx] = f2b(v);
          } else if (seg == 1) {
            of0[idx] = v;
            ob1[idx] = f2b(v);
          } else {
            of0[KV_ELEMS + idx] = v;
            ob2[((size_t)bh * 128 + d) * 256 + tt] = f2b(v);
          }
        }
      } else {
        float bias = bias0[n];
#pragma unroll
        for (int r = 0; r < 4; ++r) {
          int m = tile_m + wm + 16 * i + quad * 4 + r;
          float v = acc[i][j][r] + bias;
          if (mode == 0) ob0[(size_t)m * N + n] = f2b(v);
          else           of0[(size_t)m * N + n] = v;
        }
      }
    }
  }
}

// ---------------- flash attention: grid (4 qblocks, 512 bh), 4 waves -------
// wave w owns q rows qb*64 + w*16 .. +15. K/V tiles of 64 staged in LDS.
__global__ __launch_bounds__(256) void attn_kernel(
    const u16* __restrict__ qw, const u16* __restrict__ kw,
    const u16* __restrict__ vt, u16* __restrict__ yatt) {
  __shared__ __attribute__((aligned(16))) u16 Ks[64 * 136];   // rows padded +8
  __shared__ __attribute__((aligned(16))) u16 Vs[128 * 72];   // [d][j], padded
  __shared__ __attribute__((aligned(16))) u16 Ps[4 * 16 * 72];
  const int qb = blockIdx.x;
  const int bh = blockIdx.y;
  const int t = threadIdx.x;
  const int lane = t & 63, w = t >> 6;
  const int l15 = lane & 15, quad = lane >> 4;
  const int qrow0 = qb * 64 + w * 16;

  bf16x8 aq[4];
#pragma unroll
  for (int ks = 0; ks < 4; ++ks)
    aq[ks] = *(const bf16x8*)(qw + ((size_t)bh * 256 + qrow0 + l15) * 128 + ks * 32 + quad * 8);

  f32x4 o[8];
  f32x4 zero = {0.f, 0.f, 0.f, 0.f};
#pragma unroll
  for (int dt = 0; dt < 8; ++dt) o[dt] = zero;
  float mi[4] = {-1e30f, -1e30f, -1e30f, -1e30f};
  float li[4] = {0.f, 0.f, 0.f, 0.f};

  for (int j = 0; j <= qb; ++j) {
    __syncthreads();
    {
      const u16* ksrc = kw + ((size_t)bh * 256 + j * 64) * 128;
      int kr = t >> 2, kc = t & 3;
#pragma unroll
      for (int s = 0; s < 4; ++s) {
        int cb = s * 4 + kc;
        *(bf16x8*)(Ks + kr * 136 + cb * 8) = *(const bf16x8*)(ksrc + kr * 128 + cb * 8);
      }
      const u16* vsrc = vt + ((size_t)bh * 128 + (t >> 1)) * 256 + j * 64;
      int vh = t & 1;
#pragma unroll
      for (int s = 0; s < 4; ++s) {
        int cb = s * 2 + vh;
        *(bf16x8*)(Vs + (t >> 1) * 72 + cb * 8) = *(const bf16x8*)(vsrc + cb * 8);
      }
    }
    __syncthreads();

    f32x4 s4[4];
#pragma unroll
    for (int nt = 0; nt < 4; ++nt) s4[nt] = zero;
#pragma unroll
    for (int nt = 0; nt < 4; ++nt)
#pragma unroll
      for (int ks = 0; ks < 4; ++ks) {
        bf16x8 bk8 = *(const bf16x8*)(Ks + (nt * 16 + l15) * 136 + ks * 32 + quad * 8);
        s4[nt] = __builtin_amdgcn_mfma_f32_16x16x32_bf16(aq[ks], bk8, s4[nt], 0, 0, 0);
      }

    const float sc = 0.08838834764831845f;  // 1/sqrt(128)
    const bool diag = (j == qb);
#pragma unroll
    for (int nt = 0; nt < 4; ++nt) {
      int coln = j * 64 + nt * 16 + l15;
#pragma unroll
      for (int r = 0; r < 4; ++r) {
        float sv = s4[nt][r] * sc;
        if (diag && coln > (qrow0 + quad * 4 + r)) sv = -1e30f;
        s4[nt][r] = sv;
      }
    }

#pragma unroll
    for (int r = 0; r < 4; ++r) {
      float mx = fmaxf(fmaxf(s4[0][r], s4[1][r]), fmaxf(s4[2][r], s4[3][r]));
#pragma unroll
      for (int off = 1; off < 16; off <<= 1)
        mx = fmaxf(mx, __shfl_xor(mx, off, 64));
      float mnew = fmaxf(mi[r], mx);
      float alpha = __expf(mi[r] - mnew);
      float sum = 0.f;
#pragma unroll
      for (int nt = 0; nt < 4; ++nt) {
        float p = __expf(s4[nt][r] - mnew);
        s4[nt][r] = p;
        sum += p;
      }
#pragma unroll
      for (int off = 1; off < 16; off <<= 1)
        sum += __shfl_xor(sum, off, 64);
      li[r] = li[r] * alpha + sum;
      mi[r] = mnew;
#pragma unroll
      for (int dt = 0; dt < 8; ++dt) o[dt][r] *= alpha;
    }

    // P (C-layout fp32) -> per-wave LDS -> A-operand bf16 frags
    u16* pw = Ps + w * 16 * 72;
#pragma unroll
    for (int nt = 0; nt < 4; ++nt)
#pragma unroll
      for (int r = 0; r < 4; ++r)
        pw[(quad * 4 + r) * 72 + nt * 16 + l15] = f2b(s4[nt][r]);
    asm volatile("s_waitcnt lgkmcnt(0)" ::: "memory");  // wave-local LDS RAW

    bf16x8 ap[2];
#pragma unroll
    for (int k2 = 0; k2 < 2; ++k2)
      ap[k2] = *(const bf16x8*)(pw + l15 * 72 + k2 * 32 + quad * 8);
#pragma unroll
    for (int dt = 0; dt < 8; ++dt)
#pragma unroll
      for (int k2 = 0; k2 < 2; ++k2) {
        bf16x8 bv8 = *(const bf16x8*)(Vs + (dt * 16 + l15) * 72 + k2 * 32 + quad * 8);
        o[dt] = __builtin_amdgcn_mfma_f32_16x16x32_bf16(ap[k2], bv8, o[dt], 0, 0, 0);
      }
  }

  const int b = bh >> 3, h = bh & 7;
#pragma unroll
  for (int r = 0; r < 4; ++r) {
    float inv = 1.0f / li[r];
    int tt = qrow0 + quad * 4 + r;
    size_t rowbase = ((size_t)b * 256 + tt) * 1024 + h * 128;
#pragma unroll
    for (int dt = 0; dt < 8; ++dt)
      yatt[rowbase + dt * 16 + l15] = f2b(o[dt][r] * inv);
  }
}

extern "C" void kernel_launch(void* const* d_in, const int* in_sizes, int n_in,
                              void* d_out, int out_size, void* d_ws, size_t ws_size,
                              hipStream_t stream) {
  const float* x      = (const float*)d_in[0];
  const float* conv_w = (const float*)d_in[1];
  const float* conv_b = (const float*)d_in[2];
  const float* Wq     = (const float*)d_in[3];
  const float* bq     = (const float*)d_in[4];
  const float* Wk     = (const float*)d_in[5];
  const float* bk     = (const float*)d_in[6];
  const float* Wv     = (const float*)d_in[7];
  const float* bv     = (const float*)d_in[8];
  const float* Wp     = (const float*)d_in[9];
  const float* bp     = (const float*)d_in[10];
  float* out = (float*)d_out;

  char* ws = (char*)d_ws;
  size_t off = 0;
  u16* A_patch = (u16*)(ws + off); off += (size_t)16384 * 256 * 2;   // 8 MB
  u16* Wc      = (u16*)(ws + off); off += (size_t)1024 * 256 * 2;    // 0.5 MB
  u16* Wqkv_t  = (u16*)(ws + off); off += (size_t)3072 * 1024 * 2;   // 6 MB
  u16* Wp_t    = (u16*)(ws + off); off += (size_t)1024 * 1024 * 2;   // 2 MB
  u16* tok     = (u16*)(ws + off); off += (size_t)16384 * 1024 * 2;  // 32 MB
  u16* q_ws    = (u16*)(ws + off); off += (size_t)KV_ELEMS * 2;      // 32 MB
  u16* k_ws    = (u16*)(ws + off); off += (size_t)KV_ELEMS * 2;      // 32 MB
  u16* v_t     = (u16*)(ws + off); off += (size_t)KV_ELEMS * 2;      // 32 MB
  u16* y_att   = tok;  // tok dead after QKV GEMM; alias. total ws: 144.5 MB

  patchify_kernel<<<4096, 256, 0, stream>>>(x, A_patch);
  castw_kernel<<<256, 256, 0, stream>>>(conv_w, Wc);
  transpose_w_kernel<<<dim3(32, 32, 4), dim3(32, 8), 0, stream>>>(
      Wq, Wk, Wv, Wp, Wqkv_t, Wp_t);
  gemm_kernel<<<dim3(128, 8), 256, 0, stream>>>(
      A_patch, Wc, 256, 1024, 0, conv_b, nullptr, nullptr,
      tok, nullptr, nullptr, nullptr);
  gemm_kernel<<<dim3(128, 24), 256, 0, stream>>>(
      tok, Wqkv_t, 1024, 3072, 1, bq, bk, bv,
      q_ws, k_ws, v_t, out + Y_ELEMS);
  attn_kernel<<<dim3(4, 512), 256, 0, stream>>>(q_ws, k_ws, v_t, y_att);
  gemm_kernel<<<dim3(128, 8), 256, 0, stream>>>(
      y_att, Wp_t, 1024, 1024, 2, bp, nullptr, nullptr,
      nullptr, nullptr, nullptr, out);
}

// Round 3
// 526.336 us; speedup vs baseline: 1.0976x; 1.0976x over previous
//
#include <hip/hip_runtime.h>

// Round 2: de-fat the QKV epilogue. All q/k/v stores are uniform [bh,t,d] bf16
// (+ coalesced fp32 present for k,v); the v-transpose moved into the attention
// kernel's LDS staging (packed u32 j-pair writes, conflict-free). v_t buffer
// eliminated. GEMM K-loop unchanged (m97 structure, 128x128, BK=32,
// global_load_lds w=16, mfma_f32_16x16x32_bf16).

typedef unsigned short u16;
typedef unsigned int u32;
typedef __attribute__((ext_vector_type(8))) short bf16x8;
typedef __attribute__((ext_vector_type(4))) float f32x4;
typedef __attribute__((ext_vector_type(4))) u16 u16x4;

#define Y_ELEMS  16777216   // B*T*C = 64*256*1024
#define KV_ELEMS 16777216   // B*H*T*D

__device__ __forceinline__ u16 f2b(float f) {
  u32 u = __float_as_uint(f);
  u32 r = u + 0x7fffu + ((u >> 16) & 1u);
  return (u16)(r >> 16);
}

__device__ __forceinline__ void gl_lds16(const u16* g, u16* l) {
  __builtin_amdgcn_global_load_lds(
      (__attribute__((address_space(1))) void*)g,
      (__attribute__((address_space(3))) void*)l, 16, 0, 0);
}

// ---------------- patchify: x[64,1,256,256] -> A_patch bf16 [16384,256] ----
__global__ __launch_bounds__(256) void patchify_kernel(
    const float* __restrict__ x, u16* __restrict__ ap) {
  int tid = blockIdx.x * 256 + threadIdx.x;
  float4 v = ((const float4*)x)[tid];
  int col4 = tid & 63;
  int row  = (tid >> 6) & 255;
  int b    = tid >> 14;
  int py = row >> 4, ky = row & 15;
  int col = col4 << 2;
  int px = col >> 4, kx = col & 15;
  size_t dst = ((size_t)(b * 256 + py * 16 + px)) * 256 + ky * 16 + kx;
  u16x4 o = { f2b(v.x), f2b(v.y), f2b(v.z), f2b(v.w) };
  *(u16x4*)(ap + dst) = o;
}

// ---------------- conv_w [1024,256] fp32 -> bf16 (already N x K) -----------
__global__ __launch_bounds__(256) void castw_kernel(
    const float* __restrict__ w, u16* __restrict__ o) {
  int tid = blockIdx.x * 256 + threadIdx.x;
  float4 v = ((const float4*)w)[tid];
  u16x4 q = { f2b(v.x), f2b(v.y), f2b(v.z), f2b(v.w) };
  *(u16x4*)(o + (size_t)tid * 4) = q;
}

// ---------------- transpose Wq/Wk/Wv -> Wqkv_t [3072,1024] bf16, Wp -> Wp_t -
__global__ __launch_bounds__(256) void transpose_w_kernel(
    const float* __restrict__ Wq, const float* __restrict__ Wk,
    const float* __restrict__ Wv, const float* __restrict__ Wp,
    u16* __restrict__ Wqkv_t, u16* __restrict__ Wp_t) {
  __shared__ float tile[32][33];
  int z = blockIdx.z;
  const float* W = (z == 0) ? Wq : (z == 1) ? Wk : (z == 2) ? Wv : Wp;
  u16* dst = (z < 3) ? (Wqkv_t + (size_t)z * 1024 * 1024) : Wp_t;
  int x0 = blockIdx.x * 32, y0 = blockIdx.y * 32;
  int tx = threadIdx.x, ty = threadIdx.y;
#pragma unroll
  for (int i = ty; i < 32; i += 8)
    tile[i][tx] = W[(size_t)(y0 + i) * 1024 + x0 + tx];
  __syncthreads();
#pragma unroll
  for (int i = ty; i < 32; i += 8)
    dst[(size_t)(x0 + i) * 1024 + y0 + tx] = f2b(tile[tx][i]);
}

// ---------------- NT GEMM: A[M,K] bf16 row-major, Bt[N,K] bf16 row-major ---
// mode 0: tok = A*B + bias0 -> ob0 bf16 [M,N]
// mode 1: fused qkv (N=3072): uniform bf16 [bh,t,d] into ob0/ob1/ob2 per seg;
//         seg1/2 additionally write fp32 present (of0 + (seg-1)*KV_ELEMS).
// mode 2: y = A*B + bias0 -> of0 fp32 [M,N]
__global__ __launch_bounds__(256) void gemm_kernel(
    const u16* __restrict__ A, const u16* __restrict__ Bt,
    int K, int N, int mode,
    const float* __restrict__ bias0, const float* __restrict__ bias1,
    const float* __restrict__ bias2,
    u16* __restrict__ ob0, u16* __restrict__ ob1, u16* __restrict__ ob2,
    float* __restrict__ of0) {
  __shared__ __attribute__((aligned(16))) u16 As[128 * 32];
  __shared__ __attribute__((aligned(16))) u16 Bs[128 * 32];
  const int t = threadIdx.x;
  const int rr = t >> 2;
  const int c8 = (t & 3) << 3;
  const int lane = t & 63;
  const int w = t >> 6;
  const int wm = (w & 1) << 6, wn = (w >> 1) << 6;
  const int l15 = lane & 15, quad = lane >> 4;
  const int tile_m = blockIdx.x * 128, tile_n = blockIdx.y * 128;

  f32x4 acc[4][4];
  f32x4 zero = {0.f, 0.f, 0.f, 0.f};
#pragma unroll
  for (int i = 0; i < 4; ++i)
#pragma unroll
    for (int j = 0; j < 4; ++j) acc[i][j] = zero;

  const u16* gA0 = A + (size_t)(tile_m + rr) * K + c8;
  const u16* gA1 = A + (size_t)(tile_m + 64 + rr) * K + c8;
  const u16* gB0 = Bt + (size_t)(tile_n + rr) * K + c8;
  const u16* gB1 = Bt + (size_t)(tile_n + 64 + rr) * K + c8;
  u16* lA0 = As + rr * 32 + c8;
  u16* lA1 = As + (64 + rr) * 32 + c8;
  u16* lB0 = Bs + rr * 32 + c8;
  u16* lB1 = Bs + (64 + rr) * 32 + c8;

  for (int k0 = 0; k0 < K; k0 += 32) {
    __syncthreads();
    gl_lds16(gA0 + k0, lA0);
    gl_lds16(gA1 + k0, lA1);
    gl_lds16(gB0 + k0, lB0);
    gl_lds16(gB1 + k0, lB1);
    __syncthreads();
    bf16x8 af[4], bfr[4];
#pragma unroll
    for (int i = 0; i < 4; ++i)
      af[i] = *(const bf16x8*)(As + (wm + 16 * i + l15) * 32 + quad * 8);
#pragma unroll
    for (int j = 0; j < 4; ++j)
      bfr[j] = *(const bf16x8*)(Bs + (wn + 16 * j + l15) * 32 + quad * 8);
#pragma unroll
    for (int i = 0; i < 4; ++i)
#pragma unroll
      for (int j = 0; j < 4; ++j)
        acc[i][j] = __builtin_amdgcn_mfma_f32_16x16x32_bf16(af[i], bfr[j], acc[i][j], 0, 0, 0);
  }

  if (mode == 1) {
    // whole block lives in one segment: tile_n is a multiple of 128,
    // segment boundary is 1024 -> seg is block-uniform.
    const int seg = tile_n >> 10;
    const float* bptr = (seg == 0) ? bias0 : (seg == 1) ? bias1 : bias2;
    u16* ob = (seg == 0) ? ob0 : (seg == 1) ? ob1 : ob2;
    float* pf = of0 + (size_t)(seg ? (seg - 1) : 0) * KV_ELEMS;
#pragma unroll
    for (int i = 0; i < 4; ++i) {
#pragma unroll
      for (int j = 0; j < 4; ++j) {
        int nn = (tile_n & 1023) + wn + 16 * j + l15;
        float bias = bptr[nn];
        int h = nn >> 7, d = nn & 127;
#pragma unroll
        for (int r = 0; r < 4; ++r) {
          int m = tile_m + wm + 16 * i + quad * 4 + r;
          int bb = m >> 8, tt = m & 255;
          size_t idx = ((size_t)(bb * 8 + h) * 256 + tt) * 128 + d;
          float v = acc[i][j][r] + bias;
          ob[idx] = f2b(v);
          if (seg) pf[idx] = v;
        }
      }
    }
  } else {
#pragma unroll
    for (int i = 0; i < 4; ++i) {
#pragma unroll
      for (int j = 0; j < 4; ++j) {
        int n = tile_n + wn + 16 * j + l15;
        float bias = bias0[n];
#pragma unroll
        for (int r = 0; r < 4; ++r) {
          int m = tile_m + wm + 16 * i + quad * 4 + r;
          float v = acc[i][j][r] + bias;
          if (mode == 0) ob0[(size_t)m * N + n] = f2b(v);
          else           of0[(size_t)m * N + n] = v;
        }
      }
    }
  }
}

// ---------------- flash attention: grid (4 qblocks, 512 bh), 4 waves -------
// wave w owns q rows qb*64 + w*16 .. +15. K/V tiles of 64 staged in LDS.
// V is staged transposed ([d][j]) from the natural [bh,t,d] buffer via
// packed-u32 LDS writes (j-pair per dword; conflict-free).
__global__ __launch_bounds__(256) void attn_kernel(
    const u16* __restrict__ qw, const u16* __restrict__ kw,
    const u16* __restrict__ vw, u16* __restrict__ yatt) {
  __shared__ __attribute__((aligned(16))) u16 Ks[64 * 136];   // rows padded +8
  __shared__ __attribute__((aligned(16))) u16 Vs[128 * 72];   // [d][j], padded
  __shared__ __attribute__((aligned(16))) u16 Ps[4 * 16 * 72];
  const int qb = blockIdx.x;
  const int bh = blockIdx.y;
  const int t = threadIdx.x;
  const int lane = t & 63, w = t >> 6;
  const int l15 = lane & 15, quad = lane >> 4;
  const int qrow0 = qb * 64 + w * 16;

  bf16x8 aq[4];
#pragma unroll
  for (int ks = 0; ks < 4; ++ks)
    aq[ks] = *(const bf16x8*)(qw + ((size_t)bh * 256 + qrow0 + l15) * 128 + ks * 32 + quad * 8);

  f32x4 o[8];
  f32x4 zero = {0.f, 0.f, 0.f, 0.f};
#pragma unroll
  for (int dt = 0; dt < 8; ++dt) o[dt] = zero;
  float mi[4] = {-1e30f, -1e30f, -1e30f, -1e30f};
  float li[4] = {0.f, 0.f, 0.f, 0.f};

  const int jp = (t & 31) * 2;    // V staging: row pair within the 64-tile
  const int db = (t >> 5) * 16;   // V staging: 16 d values

  for (int j = 0; j <= qb; ++j) {
    __syncthreads();
    {
      const u16* ksrc = kw + ((size_t)bh * 256 + j * 64) * 128;
      int kr = t >> 2, kc = t & 3;
#pragma unroll
      for (int s = 0; s < 4; ++s) {
        int cb = s * 4 + kc;
        *(bf16x8*)(Ks + kr * 136 + cb * 8) = *(const bf16x8*)(ksrc + kr * 128 + cb * 8);
      }
      // V: read rows jp, jp+1 (16 d each), write transposed packed pairs.
      const u16* vsrc = vw + ((size_t)bh * 256 + j * 64) * 128;
      bf16x8 r0a = *(const bf16x8*)(vsrc + (size_t)jp * 128 + db);
      bf16x8 r0b = *(const bf16x8*)(vsrc + (size_t)jp * 128 + db + 8);
      bf16x8 r1a = *(const bf16x8*)(vsrc + (size_t)(jp + 1) * 128 + db);
      bf16x8 r1b = *(const bf16x8*)(vsrc + (size_t)(jp + 1) * 128 + db + 8);
#pragma unroll
      for (int dd = 0; dd < 8; ++dd) {
        u32 p = (u32)(u16)r0a[dd] | ((u32)(u16)r1a[dd] << 16);
        *(u32*)(Vs + (db + dd) * 72 + jp) = p;
      }
#pragma unroll
      for (int dd = 0; dd < 8; ++dd) {
        u32 p = (u32)(u16)r0b[dd] | ((u32)(u16)r1b[dd] << 16);
        *(u32*)(Vs + (db + 8 + dd) * 72 + jp) = p;
      }
    }
    __syncthreads();

    f32x4 s4[4];
#pragma unroll
    for (int nt = 0; nt < 4; ++nt) s4[nt] = zero;
#pragma unroll
    for (int nt = 0; nt < 4; ++nt)
#pragma unroll
      for (int ks = 0; ks < 4; ++ks) {
        bf16x8 bk8 = *(const bf16x8*)(Ks + (nt * 16 + l15) * 136 + ks * 32 + quad * 8);
        s4[nt] = __builtin_amdgcn_mfma_f32_16x16x32_bf16(aq[ks], bk8, s4[nt], 0, 0, 0);
      }

    const float sc = 0.08838834764831845f;  // 1/sqrt(128)
    const bool diag = (j == qb);
#pragma unroll
    for (int nt = 0; nt < 4; ++nt) {
      int coln = j * 64 + nt * 16 + l15;
#pragma unroll
      for (int r = 0; r < 4; ++r) {
        float sv = s4[nt][r] * sc;
        if (diag && coln > (qrow0 + quad * 4 + r)) sv = -1e30f;
        s4[nt][r] = sv;
      }
    }

#pragma unroll
    for (int r = 0; r < 4; ++r) {
      float mx = fmaxf(fmaxf(s4[0][r], s4[1][r]), fmaxf(s4[2][r], s4[3][r]));
#pragma unroll
      for (int off = 1; off < 16; off <<= 1)
        mx = fmaxf(mx, __shfl_xor(mx, off, 64));
      float mnew = fmaxf(mi[r], mx);
      float alpha = __expf(mi[r] - mnew);
      float sum = 0.f;
#pragma unroll
      for (int nt = 0; nt < 4; ++nt) {
        float p = __expf(s4[nt][r] - mnew);
        s4[nt][r] = p;
        sum += p;
      }
#pragma unroll
      for (int off = 1; off < 16; off <<= 1)
        sum += __shfl_xor(sum, off, 64);
      li[r] = li[r] * alpha + sum;
      mi[r] = mnew;
#pragma unroll
      for (int dt = 0; dt < 8; ++dt) o[dt][r] *= alpha;
    }

    // P (C-layout fp32) -> per-wave LDS -> A-operand bf16 frags
    u16* pw = Ps + w * 16 * 72;
#pragma unroll
    for (int nt = 0; nt < 4; ++nt)
#pragma unroll
      for (int r = 0; r < 4; ++r)
        pw[(quad * 4 + r) * 72 + nt * 16 + l15] = f2b(s4[nt][r]);
    asm volatile("s_waitcnt lgkmcnt(0)" ::: "memory");  // wave-local LDS RAW

    bf16x8 ap[2];
#pragma unroll
    for (int k2 = 0; k2 < 2; ++k2)
      ap[k2] = *(const bf16x8*)(pw + l15 * 72 + k2 * 32 + quad * 8);
#pragma unroll
    for (int dt = 0; dt < 8; ++dt)
#pragma unroll
      for (int k2 = 0; k2 < 2; ++k2) {
        bf16x8 bv8 = *(const bf16x8*)(Vs + (dt * 16 + l15) * 72 + k2 * 32 + quad * 8);
        o[dt] = __builtin_amdgcn_mfma_f32_16x16x32_bf16(ap[k2], bv8, o[dt], 0, 0, 0);
      }
  }

  const int b = bh >> 3, h = bh & 7;
#pragma unroll
  for (int r = 0; r < 4; ++r) {
    float inv = 1.0f / li[r];
    int tt = qrow0 + quad * 4 + r;
    size_t rowbase = ((size_t)b * 256 + tt) * 1024 + h * 128;
#pragma unroll
    for (int dt = 0; dt < 8; ++dt)
      yatt[rowbase + dt * 16 + l15] = f2b(o[dt][r] * inv);
  }
}

extern "C" void kernel_launch(void* const* d_in, const int* in_sizes, int n_in,
                              void* d_out, int out_size, void* d_ws, size_t ws_size,
                              hipStream_t stream) {
  const float* x      = (const float*)d_in[0];
  const float* conv_w = (const float*)d_in[1];
  const float* conv_b = (const float*)d_in[2];
  const float* Wq     = (const float*)d_in[3];
  const float* bq     = (const float*)d_in[4];
  const float* Wk     = (const float*)d_in[5];
  const float* bk     = (const float*)d_in[6];
  const float* Wv     = (const float*)d_in[7];
  const float* bv     = (const float*)d_in[8];
  const float* Wp     = (const float*)d_in[9];
  const float* bp     = (const float*)d_in[10];
  float* out = (float*)d_out;

  char* ws = (char*)d_ws;
  size_t off = 0;
  u16* A_patch = (u16*)(ws + off); off += (size_t)16384 * 256 * 2;   // 8 MB
  u16* Wc      = (u16*)(ws + off); off += (size_t)1024 * 256 * 2;    // 0.5 MB
  u16* Wqkv_t  = (u16*)(ws + off); off += (size_t)3072 * 1024 * 2;   // 6 MB
  u16* Wp_t    = (u16*)(ws + off); off += (size_t)1024 * 1024 * 2;   // 2 MB
  u16* tok     = (u16*)(ws + off); off += (size_t)16384 * 1024 * 2;  // 32 MB
  u16* q_ws    = (u16*)(ws + off); off += (size_t)KV_ELEMS * 2;      // 32 MB
  u16* k_ws    = (u16*)(ws + off); off += (size_t)KV_ELEMS * 2;      // 32 MB
  u16* v_ws    = (u16*)(ws + off); off += (size_t)KV_ELEMS * 2;      // 32 MB
  u16* y_att   = tok;  // tok dead after QKV GEMM; alias. total ws: 144.5 MB

  patchify_kernel<<<4096, 256, 0, stream>>>(x, A_patch);
  castw_kernel<<<256, 256, 0, stream>>>(conv_w, Wc);
  transpose_w_kernel<<<dim3(32, 32, 4), dim3(32, 8), 0, stream>>>(
      Wq, Wk, Wv, Wp, Wqkv_t, Wp_t);
  gemm_kernel<<<dim3(128, 8), 256, 0, stream>>>(
      A_patch, Wc, 256, 1024, 0, conv_b, nullptr, nullptr,
      tok, nullptr, nullptr, nullptr);
  gemm_kernel<<<dim3(128, 24), 256, 0, stream>>>(
      tok, Wqkv_t, 1024, 3072, 1, bq, bk, bv,
      q_ws, k_ws, v_ws, out + Y_ELEMS);
  attn_kernel<<<dim3(4, 512), 256, 0, stream>>>(q_ws, k_ws, v_ws, y_att);
  gemm_kernel<<<dim3(128, 8), 256, 0, stream>>>(
      y_att, Wp_t, 1024, 1024, 2, bp, nullptr, nullptr,
      nullptr, nullptr, nullptr, out);
}